// Round 7
// baseline (570.278 us; speedup 1.0000x reference)
//
#include <hip/hip_runtime.h>
#include <stdint.h>
#include <utility>
#include <type_traits>

// ---------------- types / helpers ----------------
using bf16x8 = __attribute__((ext_vector_type(8))) short;   // 8 x bf16 (4 VGPRs)
using f32x4  = __attribute__((ext_vector_type(4))) float;

__device__ __forceinline__ f32x4 mfma16(bf16x8 a, bf16x8 b, f32x4 c) {
  return __builtin_amdgcn_mfma_f32_16x16x32_bf16(a, b, c, 0, 0, 0);
}

__device__ __forceinline__ unsigned short f2b_rne(float f) {
  union { float f; unsigned u; } v; v.f = f;
  unsigned r = v.u + 0x7fffu + ((v.u >> 16) & 1u);
  return (unsigned short)(r >> 16);
}

__device__ __forceinline__ unsigned cvt_pk_bf16(float lo, float hi) {
  unsigned r;
  asm("v_cvt_pk_bf16_f32 %0, %1, %2" : "=v"(r) : "v"(lo), "v"(hi));
  return r;
}

__device__ __forceinline__ void gload16(const void* g, void* l) {
  __builtin_amdgcn_global_load_lds(
      (const __attribute__((address_space(1))) void*)g,
      (__attribute__((address_space(3))) void*)l, 16, 0, 0);
}

template<int N> __device__ __forceinline__ void vmwait() {
  if constexpr (N <= 0)      asm volatile("s_waitcnt vmcnt(0)" ::: "memory");
  else if constexpr (N == 1) asm volatile("s_waitcnt vmcnt(1)" ::: "memory");
  else if constexpr (N == 2) asm volatile("s_waitcnt vmcnt(2)" ::: "memory");
  else if constexpr (N == 3) asm volatile("s_waitcnt vmcnt(3)" ::: "memory");
  else                       asm volatile("s_waitcnt vmcnt(4)" ::: "memory");
}

template<class F, int... Is>
__device__ __forceinline__ void sfor_impl(F&& f, std::integer_sequence<int, Is...>) {
  (f(std::integral_constant<int, Is>{}), ...);
}
template<int N, class F>
__device__ __forceinline__ void sfor(F&& f) {
  sfor_impl(static_cast<F&&>(f), std::make_integer_sequence<int, N>{});
}

// Stage one 16-col x 32-k tile (1 KB) of W[cols][K] into a wave-private LDS slot.
// Source is pre-swizzled (XOR (ci&3)<<4 within each col's 64B k-slice) so linear LDS
// dest reads back conflict-free with the same XOR on the read side.
__device__ __forceinline__ void stage1(const unsigned short* __restrict__ W, int K,
                                       int col0, int kt, char* slot, int lane) {
  const int ci = lane >> 2, kc = lane & 3;
  const unsigned short* src = W + (size_t)(col0 + ci) * K + kt * 32
                              + (((kc * 16) ^ ((ci & 3) << 4)) >> 1);
  gload16(src, slot);   // lane's 16B lands at slot + lane*16
}

// Per-wave pipelined GEMM: acc[cg] += A[16 x K] @ W[(c0..c0+NCG*16) x K]^T
// A in LDS (row stride AS bytes, XOR (r&7)<<4); W streamed via 4-slot x 1KB wave-private
// LDS ring, 3 tiles in flight, steady-state vmcnt(2).
template<int NCG, int AS, int K>
__device__ __forceinline__ void gemm_pipe2(const unsigned short* __restrict__ W, int c0,
                                           const char* __restrict__ abuf,
                                           char* __restrict__ ring, int lane,
                                           f32x4 (&acc)[NCG]) {
  const int r = lane & 15, hi16 = (lane >> 4) << 4;
  const int swz7 = (r & 7) << 4, swz3 = (r & 3) << 4;
  constexpr int NKT = K / 32;
  constexpr int TILES = NCG * NKT;   // tile t: kt = t / NCG, cg = t % NCG
  stage1(W, K, c0 + (0 % NCG) * 16, 0 / NCG, ring + 0 * 1024, lane);
  if constexpr (TILES > 1) stage1(W, K, c0 + (1 % NCG) * 16, 1 / NCG, ring + 1 * 1024, lane);
  if constexpr (TILES > 2) stage1(W, K, c0 + (2 % NCG) * 16, 2 / NCG, ring + 2 * 1024, lane);
  bf16x8 areg;
  sfor<TILES>([&](auto tc) {
    constexpr int t = tc.value;
    constexpr int kt = t / NCG, cg = t % NCG;
    constexpr int REM = TILES - 1 - t;
    vmwait<(REM < 2 ? REM : 2)>();
    __builtin_amdgcn_sched_barrier(0);
    if constexpr (t + 3 < TILES) {
      constexpr int t3 = t + 3;
      stage1(W, K, c0 + (t3 % NCG) * 16, t3 / NCG, ring + (t3 & 3) * 1024, lane);
    }
    if constexpr (cg == 0)
      areg = *reinterpret_cast<const bf16x8*>(abuf + r * AS + ((kt * 64 + hi16) ^ swz7));
    const bf16x8 b = *reinterpret_cast<const bf16x8*>(
        ring + (t & 3) * 1024 + r * 64 + (hi16 ^ swz3));
    acc[cg] = mfma16(areg, b, acc[cg]);
  });
}

// ---------------- fp32 -> bf16 conversion ----------------
__global__ void f2b_kernel(const float* __restrict__ s, unsigned short* __restrict__ d, int n4) {
  int i = blockIdx.x * 256 + threadIdx.x;
  if (i >= n4) return;
  float4 v = reinterpret_cast<const float4*>(s)[i];
  ushort4 o;
  o.x = f2b_rne(v.x); o.y = f2b_rne(v.y); o.z = f2b_rne(v.z); o.w = f2b_rne(v.w);
  reinterpret_cast<ushort4*>(d)[i] = o;
}

// ---------------- attn/cross weight composition (fp32): W_eff = Wo @ Wv, b_eff = Wo @ bv + bo ----
__global__ __launch_bounds__(256) void compose_attn(
    const float* __restrict__ aiW, const float* __restrict__ aib,
    const float* __restrict__ aoW, const float* __restrict__ aob,
    const float* __restrict__ ciW, const float* __restrict__ cib,
    const float* __restrict__ coW, const float* __restrict__ cob,
    unsigned short* __restrict__ wEff, float* __restrict__ bEff) {
  const int mat = blockIdx.y;
  const float* Wo = (mat < 6) ? aoW + (size_t)mat * 65536 : coW;
  const float* Wv = (mat < 6) ? aiW + (size_t)mat * 196608 + 131072 : ciW + 131072;
  const float* bv = (mat < 6) ? aib + mat * 768 + 512 : cib + 512;
  const float* bo = (mat < 6) ? aob + mat * 256 : cob;
  unsigned short* Wd = wEff + (size_t)mat * 65536;
  const int m = blockIdx.x * 16 + (threadIdx.x >> 4);
  const int k0 = (threadIdx.x & 15) * 16;
  float c[16] = {};
  for (int j = 0; j < 256; ++j) {
    const float a = Wo[m * 256 + j];
    const float* Br = Wv + j * 256 + k0;
#pragma unroll
    for (int kk = 0; kk < 16; ++kk) c[kk] = fmaf(a, Br[kk], c[kk]);
  }
#pragma unroll
  for (int kk = 0; kk < 16; ++kk) Wd[m * 256 + k0 + kk] = f2b_rne(c[kk]);
  if (blockIdx.x == 0) {
    const int mm = threadIdx.x;
    float s = 0.f;
    for (int j = 0; j < 256; ++j) s = fmaf(Wo[mm * 256 + j], bv[j], s);
    bEff[mat * 256 + mm] = s + bo[mm];
  }
}

// ---------------- fused trunk v3: 2 blocks/CU, 4-slot 1KB W-rings ----------------
__global__ __launch_bounds__(512, 4) void trunk_fused(
    const unsigned short* __restrict__ xb, const unsigned short* __restrict__ pWb,
    const float* __restrict__ projb,
    const unsigned short* __restrict__ wEff, const float* __restrict__ bEff,
    const unsigned short* __restrict__ f1Wb, const float* __restrict__ f1b,
    const unsigned short* __restrict__ f2Wb, const float* __restrict__ f2bp,
    const float* __restrict__ lng, const float* __restrict__ lnb,
    unsigned short* __restrict__ hbf) {
  __shared__ char hbuf[16 * 512];        // h bf16 [16][256] swizzled (8 KB)
  __shared__ char gbuf[16 * 2048];       // g bf16 [16][1024] swizzled (32 KB); x-stage @ stride 1024
  __shared__ char ringbuf[8 * 4096];     // per-wave 4 x 1KB W-tile rings (32 KB)
  __shared__ float red[2][16][8];
  const int tid = threadIdx.x, wid = tid >> 6, lane = tid & 63;
  const int r = lane & 15, hi = lane >> 4;
  const int row0 = blockIdx.x << 4;
  const int colb = wid * 32;
  char* ring = ringbuf + wid * 4096;

  // ---- stage x rows (16 x 512 bf16) into gbuf, stride 1024, swizzled ----
#pragma unroll
  for (int i = 0; i < 2; ++i) {
    const int id = tid + i * 512, row = id >> 6, c8 = id & 63;
    bf16x8 v = *reinterpret_cast<const bf16x8*>(xb + (size_t)(row0 + row) * 512 + c8 * 8);
    *reinterpret_cast<bf16x8*>(gbuf + row * 1024 + ((c8 * 16) ^ ((row & 7) << 4))) = v;
  }
  __syncthreads();

  f32x4 hreg[2];

  auto store_hb = [&]() {
#pragma unroll
    for (int cf = 0; cf < 2; ++cf) {
      const int cb = (colb + cf * 16 + r) * 2;
#pragma unroll
      for (int j = 0; j < 4; ++j) {
        const int row = hi * 4 + j;
        *reinterpret_cast<unsigned short*>(hbuf + row * 512 + (cb ^ ((row & 7) << 4))) =
            f2b_rne(hreg[cf][j]);
      }
    }
  };

  auto ln_apply = [&](float gm0, float gm1, float bb0, float bb1) {
    float sum[4], sq[4];
#pragma unroll
    for (int j = 0; j < 4; ++j) {
      const float v0 = hreg[0][j], v1 = hreg[1][j];
      sum[j] = v0 + v1; sq[j] = v0 * v0 + v1 * v1;
    }
#pragma unroll
    for (int m = 1; m < 16; m <<= 1)
#pragma unroll
      for (int j = 0; j < 4; ++j) {
        sum[j] += __shfl_xor(sum[j], m, 64);
        sq[j]  += __shfl_xor(sq[j],  m, 64);
      }
    if (r == 0)
#pragma unroll
      for (int j = 0; j < 4; ++j) {
        red[0][hi * 4 + j][wid] = sum[j];
        red[1][hi * 4 + j][wid] = sq[j];
      }
    __syncthreads();
#pragma unroll
    for (int j = 0; j < 4; ++j) {
      const int row = hi * 4 + j;
      f32x4 p0 = *reinterpret_cast<const f32x4*>(&red[0][row][0]);
      f32x4 p1 = *reinterpret_cast<const f32x4*>(&red[0][row][4]);
      f32x4 q0 = *reinterpret_cast<const f32x4*>(&red[1][row][0]);
      f32x4 q1 = *reinterpret_cast<const f32x4*>(&red[1][row][4]);
      const float ts = p0[0]+p0[1]+p0[2]+p0[3]+p1[0]+p1[1]+p1[2]+p1[3];
      const float tq = q0[0]+q0[1]+q0[2]+q0[3]+q1[0]+q1[1]+q1[2]+q1[3];
      const float mean = ts * (1.f / 256.f);
      const float rstd = rsqrtf(tq * (1.f / 256.f) - mean * mean + 1e-5f);
      hreg[0][j] = (hreg[0][j] - mean) * rstd * gm0 + bb0;
      hreg[1][j] = (hreg[1][j] - mean) * rstd * gm1 + bb1;
    }
  };

  // ---- proj: h = x @ pW^T + b (K=512, A=x in gbuf stride 1024) ----
  {
    f32x4 acc[2] = {};
    gemm_pipe2<2, 1024, 512>(pWb, colb, gbuf, ring, lane, acc);
    const float bv0 = projb[colb + r], bv1 = projb[colb + 16 + r];
#pragma unroll
    for (int j = 0; j < 4; ++j) { hreg[0][j] = acc[0][j] + bv0; hreg[1][j] = acc[1][j] + bv1; }
  }
  store_hb();
  __syncthreads();

  for (int L = 0; L < 6; ++L) {
    const float gm0 = lng[L * 256 + colb + r],      gm1 = lng[L * 256 + colb + 16 + r];
    const float bb0 = lnb[L * 256 + colb + r],      bb1 = lnb[L * 256 + colb + 16 + r];
    // ---- attn (composed): h = LN(h + h @ W_eff^T + b_eff) ----
    {
      f32x4 acc[2] = {};
      gemm_pipe2<2, 512, 256>(wEff + (size_t)L * 65536, colb, hbuf, ring, lane, acc);
      const float be0 = bEff[L * 256 + colb + r], be1 = bEff[L * 256 + colb + 16 + r];
#pragma unroll
      for (int j = 0; j < 4; ++j) { hreg[0][j] += acc[0][j] + be0; hreg[1][j] += acc[1][j] + be1; }
    }
    ln_apply(gm0, gm1, bb0, bb1);
    store_hb();
    __syncthreads();
    // ---- ff1: g = gelu(h @ W1^T + b1)  (1024 out cols, wave owns 128) ----
    {
      f32x4 accf[8] = {};
      gemm_pipe2<8, 512, 256>(f1Wb + (size_t)L * 262144, wid * 128, hbuf, ring, lane, accf);
#pragma unroll
      for (int cf = 0; cf < 8; ++cf) {
        const int colw = wid * 128 + cf * 16 + r;
        const float bv = f1b[L * 1024 + colw];
        const int cb = colw * 2;
#pragma unroll
        for (int j = 0; j < 4; ++j) {
          float y = accf[cf][j] + bv;
          y = 0.5f * y * (1.f + erff(y * 0.70710678118654752f));
          const int row = hi * 4 + j;
          *reinterpret_cast<unsigned short*>(gbuf + row * 2048 + (cb ^ ((row & 7) << 4))) = f2b_rne(y);
        }
      }
    }
    __syncthreads();
    // ---- ff2: h = LN(h + g @ W2^T + b2)  (K=1024, A=g in gbuf stride 2048) ----
    {
      f32x4 acc[2] = {};
      gemm_pipe2<2, 2048, 1024>(f2Wb + (size_t)L * 262144, colb, gbuf, ring, lane, acc);
      const float be0 = f2bp[L * 256 + colb + r], be1 = f2bp[L * 256 + colb + 16 + r];
#pragma unroll
      for (int j = 0; j < 4; ++j) { hreg[0][j] += acc[0][j] + be0; hreg[1][j] += acc[1][j] + be1; }
    }
    ln_apply(gm0, gm1, bb0, bb1);
    store_hb();
    __syncthreads();
  }

  // ---- cross (composed, no LN): h = h + h @ Wc_eff^T + bc_eff ----
  {
    f32x4 acc[2] = {};
    gemm_pipe2<2, 512, 256>(wEff + 6ull * 65536, colb, hbuf, ring, lane, acc);
    const float be0 = bEff[1536 + colb + r], be1 = bEff[1536 + colb + 16 + r];
#pragma unroll
    for (int j = 0; j < 4; ++j) { hreg[0][j] += acc[0][j] + be0; hreg[1][j] += acc[1][j] + be1; }
  }
#pragma unroll
  for (int cf = 0; cf < 2; ++cf)
#pragma unroll
    for (int j = 0; j < 4; ++j)
      hbf[(size_t)(row0 + hi * 4 + j) * 256 + colb + cf * 16 + r] = f2b_rne(hreg[cf][j]);
}

// ---------------- phase D v3: deeper h-prefetch, cvt_pk t1 pack, setprio ----------------
__global__ __launch_bounds__(512, 2) void phase_d3(
    const unsigned short* __restrict__ hbf, const unsigned short* __restrict__ w1b,
    const float* __restrict__ b1, const float* __restrict__ lng, const float* __restrict__ lnb,
    const unsigned short* __restrict__ w2b, const float* __restrict__ b2,
    const float* __restrict__ w3, const float* __restrict__ b3,
    float* __restrict__ out) {
  __shared__ char sm[149504];
  const int tid = threadIdx.x, wid = tid >> 6, lane = tid & 63;
  const int r = lane & 15, hi = lane >> 4;
  const int sw = (r & 7) << 4;
  const int t = blockIdx.y;

  const unsigned short* w1t = w1b + (size_t)t * 32768;   // [128][256]
  const unsigned short* w2t = w2b + (size_t)t * 8192;    // [64][128]
#pragma unroll
  for (int i = 0; i < 8; ++i) {            // W1: 4096 16B chunks
    const int id = tid + i * 512;
    const int c = id >> 5, s = id & 31;
    bf16x8 v = *reinterpret_cast<const bf16x8*>(w1t + c * 256 + s * 8);
    *reinterpret_cast<bf16x8*>(sm + c * 512 + ((s * 16) ^ ((c & 7) << 4))) = v;
  }
#pragma unroll
  for (int i = 0; i < 2; ++i) {            // W2: 1024 16B chunks
    const int id = tid + i * 512;
    const int c = id >> 4, s = id & 15;
    bf16x8 v = *reinterpret_cast<const bf16x8*>(w2t + c * 128 + s * 8);
    *reinterpret_cast<bf16x8*>(sm + 65536 + c * 256 + ((s * 16) ^ ((c & 7) << 4))) = v;
  }
  {
    float v;
    if (tid < 128)      v = b1 [t * 128 + tid];
    else if (tid < 256) v = lng[t * 128 + tid - 128];
    else if (tid < 384) v = lnb[t * 128 + tid - 256];
    else if (tid < 448) v = b2 [t * 64  + tid - 384];
    else                v = w3 [t * 64  + tid - 448];
    reinterpret_cast<float*>(sm + 81920)[tid] = v;
  }
  __syncthreads();

  const float* cb1 = reinterpret_cast<const float*>(sm + 81920);
  const float* cg  = cb1 + 128;
  const float* cbe = cb1 + 256;
  const float* cb2 = cb1 + 384;
  const float* cw3 = cb1 + 448;
  char* t1w = sm + 83968 + wid * 8192;
  const float b3t = b3[t];
  const int token_b0 = blockIdx.x * 1024;

  for (int tile = 0; tile < 2; ++tile) {
    const int B0 = token_b0 + tile * 512 + wid * 64;

    f32x4 acc1[8][4] = {};
    bf16x8 bc[4], bn[4], b2r[4];
#pragma unroll
    for (int bf = 0; bf < 4; ++bf)
      bc[bf] = *reinterpret_cast<const bf16x8*>(hbf + (size_t)(B0 + bf * 16 + r) * 256 + hi * 8);
#pragma unroll
    for (int bf = 0; bf < 4; ++bf)
      bn[bf] = *reinterpret_cast<const bf16x8*>(hbf + (size_t)(B0 + bf * 16 + r) * 256 + 32 + hi * 8);
#pragma unroll
    for (int ks = 0; ks < 8; ++ks) {
      bf16x8 a[8];
#pragma unroll
      for (int cf = 0; cf < 8; ++cf)
        a[cf] = *reinterpret_cast<const bf16x8*>(sm + (cf * 16 + r) * 512 + ((ks * 64 + hi * 16) ^ sw));
      if (ks < 6) {
#pragma unroll
        for (int bf = 0; bf < 4; ++bf)
          b2r[bf] = *reinterpret_cast<const bf16x8*>(hbf + (size_t)(B0 + bf * 16 + r) * 256 + (ks + 2) * 32 + hi * 8);
      }
      __builtin_amdgcn_s_setprio(1);
#pragma unroll
      for (int cf = 0; cf < 8; ++cf)
#pragma unroll
        for (int bf = 0; bf < 4; ++bf)
          acc1[cf][bf] = mfma16(a[cf], bc[bf], acc1[cf][bf]);
      __builtin_amdgcn_s_setprio(0);
#pragma unroll
      for (int bf = 0; bf < 4; ++bf) { bc[bf] = bn[bf]; bn[bf] = b2r[bf]; }
    }

#pragma unroll
    for (int cf = 0; cf < 8; ++cf) {
      f32x4 b1v = *reinterpret_cast<const f32x4*>(cb1 + cf * 16 + hi * 4);
#pragma unroll
      for (int bf = 0; bf < 4; ++bf) acc1[cf][bf] += b1v;
    }

    float mu[4], rsd[4];
#pragma unroll
    for (int bf = 0; bf < 4; ++bf) {
      float s = 0.f, s2 = 0.f;
#pragma unroll
      for (int cf = 0; cf < 8; ++cf)
#pragma unroll
        for (int j = 0; j < 4; ++j) { float v = acc1[cf][bf][j]; s += v; s2 += v * v; }
      s  += __shfl_xor(s, 16, 64);  s  += __shfl_xor(s, 32, 64);
      s2 += __shfl_xor(s2, 16, 64); s2 += __shfl_xor(s2, 32, 64);
      const float m = s * (1.f / 128.f);
      mu[bf] = m;
      rsd[bf] = rsqrtf(s2 * (1.f / 128.f) - m * m + 1e-5f);
    }

    f32x4 acc2[4][4] = {};
#pragma unroll
    for (int half = 0; half < 2; ++half) {
#pragma unroll
      for (int cf = 0; cf < 8; ++cf) {
        f32x4 gv = *reinterpret_cast<const f32x4*>(cg  + cf * 16 + hi * 4);
        f32x4 bv = *reinterpret_cast<const f32x4*>(cbe + cf * 16 + hi * 4);
#pragma unroll
        for (int bl = 0; bl < 2; ++bl) {
          const int bf = half * 2 + bl;
          float y0 = fmaxf((acc1[cf][bf][0] - mu[bf]) * rsd[bf] * gv[0] + bv[0], 0.f);
          float y1 = fmaxf((acc1[cf][bf][1] - mu[bf]) * rsd[bf] * gv[1] + bv[1], 0.f);
          float y2 = fmaxf((acc1[cf][bf][2] - mu[bf]) * rsd[bf] * gv[2] + bv[2], 0.f);
          float y3 = fmaxf((acc1[cf][bf][3] - mu[bf]) * rsd[bf] * gv[3] + bv[3], 0.f);
          uint2 pk;
          pk.x = cvt_pk_bf16(y0, y1);
          pk.y = cvt_pk_bf16(y2, y3);
          *reinterpret_cast<uint2*>(t1w + (bl * 16 + r) * 256 + ((cf * 32 + hi * 8) ^ sw)) = pk;
        }
      }
#pragma unroll
      for (int ks = 0; ks < 4; ++ks) {
        bf16x8 a2[4];
#pragma unroll
        for (int cf2 = 0; cf2 < 4; ++cf2)
          a2[cf2] = *reinterpret_cast<const bf16x8*>(sm + 65536 + (cf2 * 16 + r) * 256 + ((ks * 64 + hi * 16) ^ sw));
        __builtin_amdgcn_s_setprio(1);
#pragma unroll
        for (int bl = 0; bl < 2; ++bl) {
          bf16x8 bb = *reinterpret_cast<const bf16x8*>(t1w + (bl * 16 + r) * 256 + ((ks * 64 + hi * 16) ^ sw));
#pragma unroll
          for (int cf2 = 0; cf2 < 4; ++cf2)
            acc2[cf2][half * 2 + bl] = mfma16(a2[cf2], bb, acc2[cf2][half * 2 + bl]);
        }
        __builtin_amdgcn_s_setprio(0);
      }
    }

    float s[4] = {0.f, 0.f, 0.f, 0.f};
#pragma unroll
    for (int cf2 = 0; cf2 < 4; ++cf2) {
      f32x4 b2v = *reinterpret_cast<const f32x4*>(cb2 + cf2 * 16 + hi * 4);
      f32x4 w3v = *reinterpret_cast<const f32x4*>(cw3 + cf2 * 16 + hi * 4);
#pragma unroll
      for (int bf = 0; bf < 4; ++bf)
#pragma unroll
        for (int j = 0; j < 4; ++j)
          s[bf] += fmaxf(acc2[cf2][bf][j] + b2v[j], 0.f) * w3v[j];
    }
#pragma unroll
    for (int bf = 0; bf < 4; ++bf) {
      s[bf] += __shfl_xor(s[bf], 16, 64);
      s[bf] += __shfl_xor(s[bf], 32, 64);
      if (hi == 0) out[(size_t)(B0 + bf * 16 + r) * 424 + t] = s[bf] + b3t;
    }
  }
}

// ---------------- host launch ----------------
extern "C" void kernel_launch(void* const* d_in, const int* in_sizes, int n_in,
                              void* d_out, int out_size, void* d_ws, size_t ws_size,
                              hipStream_t stream) {
  const float* x     = (const float*)d_in[0];
  const float* projW = (const float*)d_in[1];
  const float* projb = (const float*)d_in[2];
  const float* aiW   = (const float*)d_in[3];
  const float* aib   = (const float*)d_in[4];
  const float* aoW   = (const float*)d_in[5];
  const float* aob   = (const float*)d_in[6];
  const float* lng   = (const float*)d_in[7];
  const float* lnbp  = (const float*)d_in[8];
  const float* f1W   = (const float*)d_in[9];
  const float* f1b   = (const float*)d_in[10];
  const float* f2W   = (const float*)d_in[11];
  const float* f2bp  = (const float*)d_in[12];
  const float* ciW   = (const float*)d_in[13];
  const float* cib   = (const float*)d_in[14];
  const float* coW   = (const float*)d_in[15];
  const float* cob   = (const float*)d_in[16];
  const float* tpW1  = (const float*)d_in[17];
  const float* tpb1  = (const float*)d_in[18];
  const float* tplng = (const float*)d_in[19];
  const float* tplnb = (const float*)d_in[20];
  const float* tpW2  = (const float*)d_in[21];
  const float* tpb2  = (const float*)d_in[22];
  const float* tpW3  = (const float*)d_in[23];
  const float* tpb3  = (const float*)d_in[24];
  float* out = (float*)d_out;

  char* ws = (char*)d_ws;
  size_t off = 0;
  auto alloc = [&](size_t n) { char* p = ws + off; off = (off + n + 255) & ~(size_t)255; return p; };
  unsigned short* xb   = (unsigned short*)alloc(4096ull * 512 * 2);
  unsigned short* pWb  = (unsigned short*)alloc(256ull * 512 * 2);
  unsigned short* f1Wb = (unsigned short*)alloc(6ull * 1024 * 256 * 2);
  unsigned short* f2Wb = (unsigned short*)alloc(6ull * 256 * 1024 * 2);
  unsigned short* W1b  = (unsigned short*)alloc(424ull * 128 * 256 * 2);
  unsigned short* W2b  = (unsigned short*)alloc(424ull * 64 * 128 * 2);
  unsigned short* wEff = (unsigned short*)alloc(7ull * 256 * 256 * 2);
  float*          bEff = (float*)alloc(7ull * 256 * 4);
  unsigned short* hbf  = (unsigned short*)alloc(4096ull * 256 * 2);

  auto conv = [&](const float* s, unsigned short* d, size_t n) {
    int n4 = (int)(n >> 2);
    f2b_kernel<<<dim3((n4 + 255) / 256), dim3(256), 0, stream>>>(s, d, n4);
  };
  compose_attn<<<dim3(16, 7), dim3(256), 0, stream>>>(aiW, aib, aoW, aob, ciW, cib, coW, cob, wEff, bEff);
  conv(x, xb, 4096ull * 512);
  conv(projW, pWb, 256ull * 512);
  conv(f1W, f1Wb, 6ull * 1024 * 256);
  conv(f2W, f2Wb, 6ull * 256 * 1024);
  conv(tpW1, W1b, 424ull * 128 * 256);
  conv(tpW2, W2b, 424ull * 64 * 128);

  // whole trunk in one launch: 256 blocks x 16 rows
  trunk_fused<<<dim3(256), dim3(512), 0, stream>>>(
      xb, pWb, projb, wEff, bEff, f1Wb, f1b, f2Wb, f2bp, lng, lnbp, hbf);

  // phase D: fused per-token MLP -> out (4096 x 424)
  phase_d3<<<dim3(4, 424), dim3(512), 0, stream>>>(hbf, W1b, tpb1, tplng, tplnb, W2b, tpb2, tpW3, tpb3, out);
}

// Round 8
// 537.035 us; speedup vs baseline: 1.0619x; 1.0619x over previous
//
#include <hip/hip_runtime.h>
#include <stdint.h>
#include <utility>
#include <type_traits>

// ---------------- types / helpers ----------------
using bf16x8 = __attribute__((ext_vector_type(8))) short;   // 8 x bf16 (4 VGPRs)
using f32x4  = __attribute__((ext_vector_type(4))) float;

__device__ __forceinline__ f32x4 mfma16(bf16x8 a, bf16x8 b, f32x4 c) {
  return __builtin_amdgcn_mfma_f32_16x16x32_bf16(a, b, c, 0, 0, 0);
}

__device__ __forceinline__ unsigned short f2b_rne(float f) {
  union { float f; unsigned u; } v; v.f = f;
  unsigned r = v.u + 0x7fffu + ((v.u >> 16) & 1u);
  return (unsigned short)(r >> 16);
}

__device__ __forceinline__ void gload16(const void* g, void* l) {
  __builtin_amdgcn_global_load_lds(
      (const __attribute__((address_space(1))) void*)g,
      (__attribute__((address_space(3))) void*)l, 16, 0, 0);
}

template<int N> __device__ __forceinline__ void vmwait() {
  if constexpr (N <= 0)      asm volatile("s_waitcnt vmcnt(0)" ::: "memory");
  else if constexpr (N == 1) asm volatile("s_waitcnt vmcnt(1)" ::: "memory");
  else if constexpr (N == 2) asm volatile("s_waitcnt vmcnt(2)" ::: "memory");
  else if constexpr (N == 3) asm volatile("s_waitcnt vmcnt(3)" ::: "memory");
  else if constexpr (N == 4) asm volatile("s_waitcnt vmcnt(4)" ::: "memory");
  else                       asm volatile("s_waitcnt vmcnt(5)" ::: "memory");
}

template<class F, int... Is>
__device__ __forceinline__ void sfor_impl(F&& f, std::integer_sequence<int, Is...>) {
  (f(std::integral_constant<int, Is>{}), ...);
}
template<int N, class F>
__device__ __forceinline__ void sfor(F&& f) {
  sfor_impl(static_cast<F&&>(f), std::make_integer_sequence<int, N>{});
}

// Stage one 16-col x 32-k tile (1 KB) of W[cols][K] into a wave-private LDS slot.
// Source is pre-swizzled (XOR (ci&3)<<4 within each col's 64B k-slice) so the linear
// LDS dest reads back with the same XOR on the read side (4-way max conflict).
__device__ __forceinline__ void stage1(const unsigned short* __restrict__ W, int K,
                                       int col0, int kt, char* slot, int lane) {
  const int ci = lane >> 2, kc = lane & 3;
  const unsigned short* src = W + (size_t)(col0 + ci) * K + kt * 32
                              + (((kc * 16) ^ ((ci & 3) << 4)) >> 1);
  gload16(src, slot);   // lane's 16B lands at slot + lane*16
}

// Per-wave pipelined GEMM: acc[cg] += A[16 x K] @ W[(c0..c0+NCG*16) x K]^T
// A in LDS (row stride AS bytes, XOR (r&7)<<4); W streamed via 6-slot x 1KB wave-private
// LDS ring, depth-5 prefetch, steady-state vmcnt(4).
template<int NCG, int AS, int K>
__device__ __forceinline__ void gemm_pipe3(const unsigned short* __restrict__ W, int c0,
                                           const char* __restrict__ abuf,
                                           char* __restrict__ ring, int lane,
                                           f32x4 (&acc)[NCG]) {
  const int r = lane & 15, hi16 = (lane >> 4) << 4;
  const int swz7 = (r & 7) << 4, swz3 = (r & 3) << 4;
  constexpr int NKT = K / 32;
  constexpr int TILES = NCG * NKT;   // tile t: kt = t / NCG, cg = t % NCG
  constexpr int DEPTH = (TILES < 5) ? TILES : 5;
  sfor<DEPTH>([&](auto pc) {
    constexpr int p = pc.value;
    stage1(W, K, c0 + (p % NCG) * 16, p / NCG, ring + (p % 6) * 1024, lane);
  });
  bf16x8 areg;
  sfor<TILES>([&](auto tc) {
    constexpr int t = tc.value;
    constexpr int kt = t / NCG, cg = t % NCG;
    constexpr int REM = TILES - 1 - t;
    vmwait<(REM < 4 ? REM : 4)>();
    __builtin_amdgcn_sched_barrier(0);
    if constexpr (t + 5 < TILES) {
      constexpr int t5 = t + 5;
      stage1(W, K, c0 + (t5 % NCG) * 16, t5 / NCG, ring + (t5 % 6) * 1024, lane);
    }
    if constexpr (cg == 0)
      areg = *reinterpret_cast<const bf16x8*>(abuf + r * AS + ((kt * 64 + hi16) ^ swz7));
    const bf16x8 b = *reinterpret_cast<const bf16x8*>(
        ring + (t % 6) * 1024 + r * 64 + (hi16 ^ swz3));
    acc[cg] = mfma16(areg, b, acc[cg]);
  });
}

// ---------------- fp32 -> bf16 conversion ----------------
__global__ void f2b_kernel(const float* __restrict__ s, unsigned short* __restrict__ d, int n4) {
  int i = blockIdx.x * 256 + threadIdx.x;
  if (i >= n4) return;
  float4 v = reinterpret_cast<const float4*>(s)[i];
  ushort4 o;
  o.x = f2b_rne(v.x); o.y = f2b_rne(v.y); o.z = f2b_rne(v.z); o.w = f2b_rne(v.w);
  reinterpret_cast<ushort4*>(d)[i] = o;
}

// ---------------- attn/cross weight composition (fp32): W_eff = Wo @ Wv, b_eff = Wo @ bv + bo ----
__global__ __launch_bounds__(256) void compose_attn(
    const float* __restrict__ aiW, const float* __restrict__ aib,
    const float* __restrict__ aoW, const float* __restrict__ aob,
    const float* __restrict__ ciW, const float* __restrict__ cib,
    const float* __restrict__ coW, const float* __restrict__ cob,
    unsigned short* __restrict__ wEff, float* __restrict__ bEff) {
  const int mat = blockIdx.y;
  const float* Wo = (mat < 6) ? aoW + (size_t)mat * 65536 : coW;
  const float* Wv = (mat < 6) ? aiW + (size_t)mat * 196608 + 131072 : ciW + 131072;
  const float* bv = (mat < 6) ? aib + mat * 768 + 512 : cib + 512;
  const float* bo = (mat < 6) ? aob + mat * 256 : cob;
  unsigned short* Wd = wEff + (size_t)mat * 65536;
  const int m = blockIdx.x * 16 + (threadIdx.x >> 4);
  const int k0 = (threadIdx.x & 15) * 16;
  float c[16] = {};
  for (int j = 0; j < 256; ++j) {
    const float a = Wo[m * 256 + j];
    const float* Br = Wv + j * 256 + k0;
#pragma unroll
    for (int kk = 0; kk < 16; ++kk) c[kk] = fmaf(a, Br[kk], c[kk]);
  }
#pragma unroll
  for (int kk = 0; kk < 16; ++kk) Wd[m * 256 + k0 + kk] = f2b_rne(c[kk]);
  if (blockIdx.x == 0) {
    const int mm = threadIdx.x;
    float s = 0.f;
    for (int j = 0; j < 256; ++j) s = fmaf(Wo[mm * 256 + j], bv[j], s);
    bEff[mat * 256 + mm] = s + bo[mm];
  }
}

// ---------------- fused trunk v4: 1024 threads (16 waves = 4/SIMD), depth-5 1KB rings ----------------
// grid 256 x 1024. Block owns 16 rows for the whole trunk. Wave w owns 16 out-cols
// (64 for ff1). h master fp32 in registers (4 rows x 1 col per thread).
__global__ __launch_bounds__(1024) void trunk_fused(
    const unsigned short* __restrict__ xb, const unsigned short* __restrict__ pWb,
    const float* __restrict__ projb,
    const unsigned short* __restrict__ wEff, const float* __restrict__ bEff,
    const unsigned short* __restrict__ f1Wb, const float* __restrict__ f1b,
    const unsigned short* __restrict__ f2Wb, const float* __restrict__ f2bp,
    const float* __restrict__ lng, const float* __restrict__ lnb,
    unsigned short* __restrict__ hbf) {
  __shared__ char hbuf[16 * 512];        // h bf16 [16][256] swizzled (8 KB)
  __shared__ char gbuf[16 * 2048];       // g bf16 [16][1024] swizzled (32 KB); x-stage @ stride 1024
  __shared__ char ringbuf[16 * 6144];    // per-wave 6 x 1KB W-tile rings (96 KB)
  __shared__ float red[2][16][16];       // (2 KB)
  const int tid = threadIdx.x, wid = tid >> 6, lane = tid & 63;
  const int r = lane & 15, hi = lane >> 4;
  const int row0 = blockIdx.x << 4;
  const int col = wid * 16 + r;          // this thread's h column
  char* ring = ringbuf + wid * 6144;

  // ---- stage x rows (16 x 512 bf16) into gbuf, stride 1024, swizzled ----
  {
    const int row = tid >> 6, c8 = tid & 63;
    bf16x8 v = *reinterpret_cast<const bf16x8*>(xb + (size_t)(row0 + row) * 512 + c8 * 8);
    *reinterpret_cast<bf16x8*>(gbuf + row * 1024 + ((c8 * 16) ^ ((row & 7) << 4))) = v;
  }
  __syncthreads();

  f32x4 hreg;   // rows hi*4+j, col = wid*16+r

  auto store_hb = [&]() {
    const int cb = col * 2;
#pragma unroll
    for (int j = 0; j < 4; ++j) {
      const int row = hi * 4 + j;
      *reinterpret_cast<unsigned short*>(hbuf + row * 512 + (cb ^ ((row & 7) << 4))) =
          f2b_rne(hreg[j]);
    }
  };

  auto ln_apply = [&](float gm, float bb) {
    float sum[4], sq[4];
#pragma unroll
    for (int j = 0; j < 4; ++j) { sum[j] = hreg[j]; sq[j] = hreg[j] * hreg[j]; }
#pragma unroll
    for (int m = 1; m < 16; m <<= 1)
#pragma unroll
      for (int j = 0; j < 4; ++j) {
        sum[j] += __shfl_xor(sum[j], m, 64);
        sq[j]  += __shfl_xor(sq[j],  m, 64);
      }
    if (r == 0)
#pragma unroll
      for (int j = 0; j < 4; ++j) {
        red[0][hi * 4 + j][wid] = sum[j];
        red[1][hi * 4 + j][wid] = sq[j];
      }
    __syncthreads();
#pragma unroll
    for (int j = 0; j < 4; ++j) {
      const int row = hi * 4 + j;
      float ts = 0.f, tq = 0.f;
#pragma unroll
      for (int q = 0; q < 4; ++q) {
        f32x4 p = *reinterpret_cast<const f32x4*>(&red[0][row][q * 4]);
        f32x4 s2 = *reinterpret_cast<const f32x4*>(&red[1][row][q * 4]);
        ts += p[0] + p[1] + p[2] + p[3];
        tq += s2[0] + s2[1] + s2[2] + s2[3];
      }
      const float mean = ts * (1.f / 256.f);
      const float rstd = rsqrtf(tq * (1.f / 256.f) - mean * mean + 1e-5f);
      hreg[j] = (hreg[j] - mean) * rstd * gm + bb;
    }
  };

  // ---- proj: h = x @ pW^T + b (K=512, A=x in gbuf stride 1024) ----
  {
    f32x4 acc[1] = {};
    gemm_pipe3<1, 1024, 512>(pWb, wid * 16, gbuf, ring, lane, acc);
    const float bv = projb[col];
#pragma unroll
    for (int j = 0; j < 4; ++j) hreg[j] = acc[0][j] + bv;
  }
  store_hb();
  __syncthreads();

  for (int L = 0; L < 6; ++L) {
    const float gm = lng[L * 256 + col], bb = lnb[L * 256 + col];
    // ---- attn (composed): h = LN(h + h @ W_eff^T + b_eff) ----
    {
      f32x4 acc[1] = {};
      gemm_pipe3<1, 512, 256>(wEff + (size_t)L * 65536, wid * 16, hbuf, ring, lane, acc);
      const float be = bEff[L * 256 + col];
#pragma unroll
      for (int j = 0; j < 4; ++j) hreg[j] += acc[0][j] + be;
    }
    ln_apply(gm, bb);
    store_hb();
    __syncthreads();
    // ---- ff1: g = gelu(h @ W1^T + b1)  (1024 out cols, wave owns 64) ----
    {
      f32x4 accf[4] = {};
      gemm_pipe3<4, 512, 256>(f1Wb + (size_t)L * 262144, wid * 64, hbuf, ring, lane, accf);
#pragma unroll
      for (int cf = 0; cf < 4; ++cf) {
        const int colw = wid * 64 + cf * 16 + r;
        const float bv = f1b[L * 1024 + colw];
        const int cb = colw * 2;
#pragma unroll
        for (int j = 0; j < 4; ++j) {
          float y = accf[cf][j] + bv;
          y = 0.5f * y * (1.f + erff(y * 0.70710678118654752f));
          const int row = hi * 4 + j;
          *reinterpret_cast<unsigned short*>(gbuf + row * 2048 + (cb ^ ((row & 7) << 4))) = f2b_rne(y);
        }
      }
    }
    __syncthreads();
    // ---- ff2: h = LN(h + g @ W2^T + b2)  (K=1024, A=g in gbuf stride 2048) ----
    {
      f32x4 acc[1] = {};
      gemm_pipe3<1, 2048, 1024>(f2Wb + (size_t)L * 262144, wid * 16, gbuf, ring, lane, acc);
      const float be = f2bp[L * 256 + col];
#pragma unroll
      for (int j = 0; j < 4; ++j) hreg[j] += acc[0][j] + be;
    }
    ln_apply(gm, bb);
    store_hb();
    __syncthreads();
  }

  // ---- cross (composed, no LN): h = h + h @ Wc_eff^T + bc_eff ----
  {
    f32x4 acc[1] = {};
    gemm_pipe3<1, 512, 256>(wEff + 6ull * 65536, wid * 16, hbuf, ring, lane, acc);
    const float be = bEff[1536 + col];
#pragma unroll
    for (int j = 0; j < 4; ++j) hreg[j] += acc[0][j] + be;
  }
#pragma unroll
  for (int j = 0; j < 4; ++j)
    hbf[(size_t)(row0 + hi * 4 + j) * 256 + col] = f2b_rne(hreg[j]);
}

// ---------------- phase D v2: weight-stationary, barrier-free per-wave tiles (R3-exact) ----------------
__global__ __launch_bounds__(512, 2) void phase_d2(
    const unsigned short* __restrict__ hbf, const unsigned short* __restrict__ w1b,
    const float* __restrict__ b1, const float* __restrict__ lng, const float* __restrict__ lnb,
    const unsigned short* __restrict__ w2b, const float* __restrict__ b2,
    const float* __restrict__ w3, const float* __restrict__ b3,
    float* __restrict__ out) {
  __shared__ char sm[149504];
  const int tid = threadIdx.x, wid = tid >> 6, lane = tid & 63;
  const int r = lane & 15, hi = lane >> 4;
  const int sw = (r & 7) << 4;
  const int t = blockIdx.y;

  const unsigned short* w1t = w1b + (size_t)t * 32768;   // [128][256]
  const unsigned short* w2t = w2b + (size_t)t * 8192;    // [64][128]
#pragma unroll
  for (int i = 0; i < 8; ++i) {            // W1: 4096 16B chunks
    const int id = tid + i * 512;
    const int c = id >> 5, s = id & 31;
    bf16x8 v = *reinterpret_cast<const bf16x8*>(w1t + c * 256 + s * 8);
    *reinterpret_cast<bf16x8*>(sm + c * 512 + ((s * 16) ^ ((c & 7) << 4))) = v;
  }
#pragma unroll
  for (int i = 0; i < 2; ++i) {            // W2: 1024 16B chunks
    const int id = tid + i * 512;
    const int c = id >> 4, s = id & 15;
    bf16x8 v = *reinterpret_cast<const bf16x8*>(w2t + c * 128 + s * 8);
    *reinterpret_cast<bf16x8*>(sm + 65536 + c * 256 + ((s * 16) ^ ((c & 7) << 4))) = v;
  }
  {
    float v;
    if (tid < 128)      v = b1 [t * 128 + tid];
    else if (tid < 256) v = lng[t * 128 + tid - 128];
    else if (tid < 384) v = lnb[t * 128 + tid - 256];
    else if (tid < 448) v = b2 [t * 64  + tid - 384];
    else                v = w3 [t * 64  + tid - 448];
    reinterpret_cast<float*>(sm + 81920)[tid] = v;
  }
  __syncthreads();

  const float* cb1 = reinterpret_cast<const float*>(sm + 81920);
  const float* cg  = cb1 + 128;
  const float* cbe = cb1 + 256;
  const float* cb2 = cb1 + 384;
  const float* cw3 = cb1 + 448;
  char* t1w = sm + 83968 + wid * 8192;
  const float b3t = b3[t];
  const int token_b0 = blockIdx.x * 1024;

  for (int tile = 0; tile < 2; ++tile) {
    const int B0 = token_b0 + tile * 512 + wid * 64;

    f32x4 acc1[8][4] = {};
    bf16x8 bc[4], bn[4];
#pragma unroll
    for (int bf = 0; bf < 4; ++bf)
      bc[bf] = *reinterpret_cast<const bf16x8*>(hbf + (size_t)(B0 + bf * 16 + r) * 256 + hi * 8);
#pragma unroll
    for (int ks = 0; ks < 8; ++ks) {
      bf16x8 a[8];
#pragma unroll
      for (int cf = 0; cf < 8; ++cf)
        a[cf] = *reinterpret_cast<const bf16x8*>(sm + (cf * 16 + r) * 512 + ((ks * 64 + hi * 16) ^ sw));
      if (ks < 7) {
#pragma unroll
        for (int bf = 0; bf < 4; ++bf)
          bn[bf] = *reinterpret_cast<const bf16x8*>(hbf + (size_t)(B0 + bf * 16 + r) * 256 + (ks + 1) * 32 + hi * 8);
      }
#pragma unroll
      for (int cf = 0; cf < 8; ++cf)
#pragma unroll
        for (int bf = 0; bf < 4; ++bf)
          acc1[cf][bf] = mfma16(a[cf], bc[bf], acc1[cf][bf]);
#pragma unroll
      for (int bf = 0; bf < 4; ++bf) bc[bf] = bn[bf];
    }

#pragma unroll
    for (int cf = 0; cf < 8; ++cf) {
      f32x4 b1v = *reinterpret_cast<const f32x4*>(cb1 + cf * 16 + hi * 4);
#pragma unroll
      for (int bf = 0; bf < 4; ++bf) acc1[cf][bf] += b1v;
    }

    float mu[4], rsd[4];
#pragma unroll
    for (int bf = 0; bf < 4; ++bf) {
      float s = 0.f, s2 = 0.f;
#pragma unroll
      for (int cf = 0; cf < 8; ++cf)
#pragma unroll
        for (int j = 0; j < 4; ++j) { float v = acc1[cf][bf][j]; s += v; s2 += v * v; }
      s  += __shfl_xor(s, 16, 64);  s  += __shfl_xor(s, 32, 64);
      s2 += __shfl_xor(s2, 16, 64); s2 += __shfl_xor(s2, 32, 64);
      const float m = s * (1.f / 128.f);
      mu[bf] = m;
      rsd[bf] = rsqrtf(s2 * (1.f / 128.f) - m * m + 1e-5f);
    }

    f32x4 acc2[4][4] = {};
#pragma unroll
    for (int half = 0; half < 2; ++half) {
#pragma unroll
      for (int cf = 0; cf < 8; ++cf) {
        f32x4 gv = *reinterpret_cast<const f32x4*>(cg  + cf * 16 + hi * 4);
        f32x4 bv = *reinterpret_cast<const f32x4*>(cbe + cf * 16 + hi * 4);
#pragma unroll
        for (int bl = 0; bl < 2; ++bl) {
          const int bf = half * 2 + bl;
          unsigned o01, o23;
          {
            float y0 = fmaxf((acc1[cf][bf][0] - mu[bf]) * rsd[bf] * gv[0] + bv[0], 0.f);
            float y1 = fmaxf((acc1[cf][bf][1] - mu[bf]) * rsd[bf] * gv[1] + bv[1], 0.f);
            float y2 = fmaxf((acc1[cf][bf][2] - mu[bf]) * rsd[bf] * gv[2] + bv[2], 0.f);
            float y3 = fmaxf((acc1[cf][bf][3] - mu[bf]) * rsd[bf] * gv[3] + bv[3], 0.f);
            o01 = (unsigned)f2b_rne(y0) | ((unsigned)f2b_rne(y1) << 16);
            o23 = (unsigned)f2b_rne(y2) | ((unsigned)f2b_rne(y3) << 16);
          }
          uint2 pk; pk.x = o01; pk.y = o23;
          *reinterpret_cast<uint2*>(t1w + (bl * 16 + r) * 256 + ((cf * 32 + hi * 8) ^ sw)) = pk;
        }
      }
#pragma unroll
      for (int ks = 0; ks < 4; ++ks) {
        bf16x8 a2[4];
#pragma unroll
        for (int cf2 = 0; cf2 < 4; ++cf2)
          a2[cf2] = *reinterpret_cast<const bf16x8*>(sm + 65536 + (cf2 * 16 + r) * 256 + ((ks * 64 + hi * 16) ^ sw));
#pragma unroll
        for (int bl = 0; bl < 2; ++bl) {
          bf16x8 bb = *reinterpret_cast<const bf16x8*>(t1w + (bl * 16 + r) * 256 + ((ks * 64 + hi * 16) ^ sw));
#pragma unroll
          for (int cf2 = 0; cf2 < 4; ++cf2)
            acc2[cf2][half * 2 + bl] = mfma16(a2[cf2], bb, acc2[cf2][half * 2 + bl]);
        }
      }
    }

    float s[4] = {0.f, 0.f, 0.f, 0.f};
#pragma unroll
    for (int cf2 = 0; cf2 < 4; ++cf2) {
      f32x4 b2v = *reinterpret_cast<const f32x4*>(cb2 + cf2 * 16 + hi * 4);
      f32x4 w3v = *reinterpret_cast<const f32x4*>(cw3 + cf2 * 16 + hi * 4);
#pragma unroll
      for (int bf = 0; bf < 4; ++bf)
#pragma unroll
        for (int j = 0; j < 4; ++j)
          s[bf] += fmaxf(acc2[cf2][bf][j] + b2v[j], 0.f) * w3v[j];
    }
#pragma unroll
    for (int bf = 0; bf < 4; ++bf) {
      s[bf] += __shfl_xor(s[bf], 16, 64);
      s[bf] += __shfl_xor(s[bf], 32, 64);
      if (hi == 0) out[(size_t)(B0 + bf * 16 + r) * 424 + t] = s[bf] + b3t;
    }
  }
}

// ---------------- host launch ----------------
extern "C" void kernel_launch(void* const* d_in, const int* in_sizes, int n_in,
                              void* d_out, int out_size, void* d_ws, size_t ws_size,
                              hipStream_t stream) {
  const float* x     = (const float*)d_in[0];
  const float* projW = (const float*)d_in[1];
  const float* projb = (const float*)d_in[2];
  const float* aiW   = (const float*)d_in[3];
  const float* aib   = (const float*)d_in[4];
  const float* aoW   = (const float*)d_in[5];
  const float* aob   = (const float*)d_in[6];
  const float* lng   = (const float*)d_in[7];
  const float* lnbp  = (const float*)d_in[8];
  const float* f1W   = (const float*)d_in[9];
  const float* f1b   = (const float*)d_in[10];
  const float* f2W   = (const float*)d_in[11];
  const float* f2bp  = (const float*)d_in[12];
  const float* ciW   = (const float*)d_in[13];
  const float* cib   = (const float*)d_in[14];
  const float* coW   = (const float*)d_in[15];
  const float* cob   = (const float*)d_in[16];
  const float* tpW1  = (const float*)d_in[17];
  const float* tpb1  = (const float*)d_in[18];
  const float* tplng = (const float*)d_in[19];
  const float* tplnb = (const float*)d_in[20];
  const float* tpW2  = (const float*)d_in[21];
  const float* tpb2  = (const float*)d_in[22];
  const float* tpW3  = (const float*)d_in[23];
  const float* tpb3  = (const float*)d_in[24];
  float* out = (float*)d_out;

  char* ws = (char*)d_ws;
  size_t off = 0;
  auto alloc = [&](size_t n) { char* p = ws + off; off = (off + n + 255) & ~(size_t)255; return p; };
  unsigned short* xb   = (unsigned short*)alloc(4096ull * 512 * 2);
  unsigned short* pWb  = (unsigned short*)alloc(256ull * 512 * 2);
  unsigned short* f1Wb = (unsigned short*)alloc(6ull * 1024 * 256 * 2);
  unsigned short* f2Wb = (unsigned short*)alloc(6ull * 256 * 1024 * 2);
  unsigned short* W1b  = (unsigned short*)alloc(424ull * 128 * 256 * 2);
  unsigned short* W2b  = (unsigned short*)alloc(424ull * 64 * 128 * 2);
  unsigned short* wEff = (unsigned short*)alloc(7ull * 256 * 256 * 2);
  float*          bEff = (float*)alloc(7ull * 256 * 4);
  unsigned short* hbf  = (unsigned short*)alloc(4096ull * 256 * 2);

  auto conv = [&](const float* s, unsigned short* d, size_t n) {
    int n4 = (int)(n >> 2);
    f2b_kernel<<<dim3((n4 + 255) / 256), dim3(256), 0, stream>>>(s, d, n4);
  };
  compose_attn<<<dim3(16, 7), dim3(256), 0, stream>>>(aiW, aib, aoW, aob, ciW, cib, coW, cob, wEff, bEff);
  conv(x, xb, 4096ull * 512);
  conv(projW, pWb, 256ull * 512);
  conv(f1W, f1Wb, 6ull * 1024 * 256);
  conv(f2W, f2Wb, 6ull * 256 * 1024);
  conv(tpW1, W1b, 424ull * 128 * 256);
  conv(tpW2, W2b, 424ull * 64 * 128);

  // whole trunk in one launch: 256 blocks x 16 rows, 16 waves each
  trunk_fused<<<dim3(256), dim3(1024), 0, stream>>>(
      xb, pWb, projb, wEff, bEff, f1Wb, f1b, f2Wb, f2bp, lng, lnbp, hbf);

  // phase D: fused per-token MLP -> out (4096 x 424)
  phase_d2<<<dim3(4, 424), dim3(512), 0, stream>>>(hbf, W1b, tpb1, tplng, tplnb, W2b, tpb2, tpW3, tpb3, out);
}